// Round 16
// baseline (363.127 us; speedup 1.0000x reference)
//
#include <hip/hip_runtime.h>
#include <stdint.h>

#define NB   128    // batch
#define CC   224    // channels
#define NWIN 16     // windows
#define DH   28     // head dim
#define NHEADS 8

using bf16x8 = __attribute__((ext_vector_type(8))) short;
using u16x4  = __attribute__((ext_vector_type(4))) unsigned short;
using f32x4  = __attribute__((ext_vector_type(4))) float;

__device__ inline unsigned short f2bf(float f) {
    union { float f; unsigned u; } v; v.f = f;
    unsigned u = v.u;
    u += 0x7fffu + ((u >> 16) & 1u);
    return (unsigned short)(u >> 16);
}

// ---- prep: weights -> bf16 in MFMA-native chunk layout ----
// chunk c = (sel*14 + ntl)*7 + kk  (sel 0..3 = Q,K,V,O; ntl 0..13; kk 0..6)
// within chunk: element (lane l, j) = W[k][n],  n = ntl*16 + (l&15),
//               k = kk*32 + (l>>4)*8 + j.
// A wave's B-fragment load for (ntl,kk) is ONE contiguous 1KB read at
// wt + c*512 + l*8.
__global__ void prep_weights(const float* __restrict__ Wq, const float* __restrict__ Wk,
                             const float* __restrict__ Wv, const float* __restrict__ Wo,
                             unsigned short* __restrict__ wt) {
    int e = blockIdx.x * blockDim.x + threadIdx.x;
    if (e >= 4 * CC * CC) return;
    int c   = e >> 9;          // chunk 0..391
    int r   = e & 511;
    int l   = r >> 3, j = r & 7;
    int kk  = c % 7;
    int t   = c / 7;           // sel*14 + ntl
    int sel = t / 14, ntl = t % 14;
    int n = ntl * 16 + (l & 15);
    int k = kk * 32 + (l >> 4) * 8 + j;
    const float* W = (sel == 0) ? Wq : (sel == 1) ? Wk : (sel == 2) ? Wv : Wo;
    wt[e] = f2bf(W[k * CC + n]);
}

// ---- shared memory layout (bytes), 32-position block ----
// Rows: row = widx + 16*mc2  (widx = window 0..15, mc2 = local col 0..1)
// Overlays (barrier-separated):
//   qs region:  qs (phase1 Q out)  -> ob (phase2 out / phase3 A in)
//   xs region:  xs (x staging)     -> vt (phase1 V out, [ch][row] w=40) -> oout (w/ ks)
//   ks region:  ks (phase1 K out)  -> attw1 (phase2b, ks dead after B4) -> oout tail
#define QS_OFF   0        // ushort [32][232] = 14848 B
#define XS_OFF   14848    // max(xs [32][232]=14848, vt [224][40]=17920) = 17920 B
#define KS_OFF   32768    // ushort [32][232] = 14848 B
#define ATT_OFF  47616    // ushort [8 waves][16][20] = 5120 B
#define SMEM_BYTES 52736
// oout: float [32][225] = 28800 B at XS_OFF (14848..43647 < 47616)
// 3 blocks/CU: 3 x 52736 = 158208 <= 163840

__global__ void __launch_bounds__(512, 6) attn_fused(
    const float* __restrict__ x, const unsigned short* __restrict__ wt,
    const float* __restrict__ bo, const float* __restrict__ pos,
    const float* __restrict__ scale, float* __restrict__ out)
{
    extern __shared__ char smem[];
    unsigned short* qs   = (unsigned short*)(smem + QS_OFF);
    unsigned short* xs   = (unsigned short*)(smem + XS_OFF);
    unsigned short* ks   = (unsigned short*)(smem + KS_OFF);
    unsigned short* att  = (unsigned short*)(smem + ATT_OFF);
    unsigned short* vt   = xs;                       // after B2
    unsigned short* ob   = qs;                       // after B4
    float*          oout = (float*)(smem + XS_OFF);  // after B5 + a3f hoist

    const int tid = threadIdx.x;
    const int wv  = tid >> 6;        // wave 0..7
    const int l   = tid & 63;
    const int g   = l >> 4;          // 0..3
    const int li  = l & 15;

    // XCD-aware decode: the 4 hq-siblings of each (bi,mr) sit adjacently on
    // one XCD (bid%8 = XCD round-robin) so partial-line writes merge in L2.
    const int bid = blockIdx.x;
    const int xcd = bid & 7;
    const int idx = bid >> 3;        // 0..511 within XCD
    const int hq  = idx & 3;         // column pair {hq*2, hq*2+1}
    const int wg  = (xcd << 7) + (idx >> 2);   // 0..1023
    const int bi  = wg >> 3;
    const int mr  = wg & 7;

    // ---- prologue: stage x -> LDS bf16, rows widx + 16*mc2 ----
    {
        const float* xb = x + ((size_t)bi * CC << 10);
        for (int q = tid; q < CC * NWIN; q += 512) {
            int ch = q >> 4, wx = q & 15;
            int wi = wx >> 2, wj = wx & 3;
            int h = wi * 8 + mr, w0 = wj * 8 + hq * 2;
            float2 v2 = *(const float2*)(xb + (ch << 10) + (h << 5) + w0);
            xs[wx * 232 + ch]        = f2bf(v2.x);   // mc2 = 0
            xs[(wx + 16) * 232 + ch] = f2bf(v2.y);   // mc2 = 1
        }
    }
    const float scl = scale[0];
    __syncthreads();                                  // B1

    // ---- phase 1 A-hoist (xs dead after this) ----
    const int mt = wv & 1;
    const int arow = mt * 16 + li;
    bf16x8 a1f[7];
    #pragma unroll
    for (int kk = 0; kk < 7; ++kk)
        a1f[kk] = *(const bf16x8*)(xs + arow * 232 + kk * 32 + g * 8);
    __syncthreads();                                  // B2 (xs -> vt)

    // ---- phase 1 N-loop: Q,K,V = x @ Wt.  Dual-N; twin waves share chunk
    // streams. ASM PIN on the B0 arm: all 14 loads are issued, then the pin
    // forces B0 materialized before acc0's MFMA chain -- B1's loads return
    // under acc0's compute. (r15's named arrays alone were re-sunk by the
    // scheduler: VGPR stayed 40. Pin only B0: pinning all 14 would exceed
    // the 85-reg 6-wave budget.) ----
    for (int d = wv >> 1; d < 21; d += 4) {
        int t0 = 2 * d;
        int sel = t0 / 14, ntl0 = t0 % 14;
        const unsigned short* w0 = wt + (size_t)t0 * 3584 + l * 8;  // t0*7*512
        bf16x8 B0[7], B1[7];
        #pragma unroll
        for (int kk = 0; kk < 7; ++kk)
            B0[kk] = *(const bf16x8*)(w0 + kk * 512);
        #pragma unroll
        for (int kk = 0; kk < 7; ++kk)
            B1[kk] = *(const bf16x8*)(w0 + 3584 + kk * 512);
        #pragma unroll
        for (int kk = 0; kk < 7; ++kk)
            asm volatile("" : "+v"(B0[kk]));
        f32x4 acc0 = {0.f, 0.f, 0.f, 0.f}, acc1 = {0.f, 0.f, 0.f, 0.f};
        #pragma unroll
        for (int kk = 0; kk < 7; ++kk)
            acc0 = __builtin_amdgcn_mfma_f32_16x16x32_bf16(a1f[kk], B0[kk], acc0, 0, 0, 0);
        #pragma unroll
        for (int kk = 0; kk < 7; ++kk)
            acc1 = __builtin_amdgcn_mfma_f32_16x16x32_bf16(a1f[kk], B1[kk], acc1, 0, 0, 0);
        int colb = ntl0 * 16 + li;
        #pragma unroll
        for (int r = 0; r < 4; ++r) {
            int row = mt * 16 + g * 4 + r;
            float v0 = acc0[r], v1 = acc1[r];
            if (sel == 0) {
                qs[row * 232 + colb]      = f2bf(v0 * scl);
                qs[row * 232 + colb + 16] = f2bf(v1 * scl);
            } else if (sel == 1) {
                ks[row * 232 + colb]      = f2bf(v0);
                ks[row * 232 + colb + 16] = f2bf(v1);
            } else {
                vt[colb * 40 + row]        = f2bf(v0);   // [ch][row]
                vt[(colb + 16) * 40 + row] = f2bf(v1);
            }
        }
    }
    __syncthreads();                                  // B3

    // ---- phase 2a: QK^T for both mc2 (reads qs/ks), pos prefetch ----
    const int hd = wv;
    const int cb = hd * DH;
    float pv4[4];
    #pragma unroll
    for (int r = 0; r < 4; ++r)
        pv4[r] = pos[(hd * 16 + g * 4 + r) * 16 + li];
    f32x4 sim[2];
    #pragma unroll
    for (int mc2 = 0; mc2 < 2; ++mc2) {
        int rowq = li + mc2 * 16;
        bf16x8 aq, bk;
        const unsigned short* qp = qs + rowq * 232 + cb + g * 8;
        const unsigned short* kp = ks + rowq * 232 + cb + g * 8;
        u16x4 qlo = *(const u16x4*)qp, qhi = *(const u16x4*)(qp + 4);
        u16x4 klo = *(const u16x4*)kp, khi = *(const u16x4*)(kp + 4);
        if (g == 3) { qhi = (u16x4)0; khi = (u16x4)0; }  // k >= 28 invalid
        #pragma unroll
        for (int j = 0; j < 4; ++j) {
            aq[j] = (short)qlo[j]; aq[4 + j] = (short)qhi[j];
            bk[j] = (short)klo[j]; bk[4 + j] = (short)khi[j];
        }
        f32x4 z = {0.f, 0.f, 0.f, 0.f};
        sim[mc2] = __builtin_amdgcn_mfma_f32_16x16x32_bf16(aq, bk, z, 0, 0, 0);
    }
    __syncthreads();                                  // B4 (qs -> ob; ks dead)

    // ---- phase 2b: softmax (both mc2 interleaved) + PV (4 indep MFMAs) ----
    // No max-subtraction: s = q.k + pos is bounded (|s| ~< 6 by construction)
    // so exp(s) is safe in f32 and softmax is algebraically identical.
    // attw1 lives in the dead ks region (oout only overlays it after B5).
    {
        unsigned short* attw0 = att + wv * 320;
        unsigned short* attw1 = ks  + wv * 320;
        // hoist V-fragment loads (independent of softmax)
        bf16x8 bv00, bv01, bv10, bv11;
        if (g < 2) {
            bv00 = *(const bf16x8*)(vt + (cb + li) * 40      + g * 8);
            bv01 = *(const bf16x8*)(vt + (cb + 16 + li) * 40 + g * 8);
            bv10 = *(const bf16x8*)(vt + (cb + li) * 40      + 16 + g * 8);
            bv11 = *(const bf16x8*)(vt + (cb + 16 + li) * 40 + 16 + g * 8);
        } else {
            bv00 = (bf16x8)0; bv01 = (bf16x8)0; bv10 = (bf16x8)0; bv11 = (bf16x8)0;
        }
        // softmax: 8 independent rows (2 mc2 x 4 r), chains interleave
        float ev[2][4];
        #pragma unroll
        for (int mc2 = 0; mc2 < 2; ++mc2)
            #pragma unroll
            for (int r = 0; r < 4; ++r)
                ev[mc2][r] = __expf(sim[mc2][r] + pv4[r]);
        #pragma unroll
        for (int mc2 = 0; mc2 < 2; ++mc2) {
            unsigned short* aw = mc2 ? attw1 : attw0;
            #pragma unroll
            for (int r = 0; r < 4; ++r) {
                float sm = ev[mc2][r];
                sm += __shfl_xor(sm, 1, 16);
                sm += __shfl_xor(sm, 2, 16);
                sm += __shfl_xor(sm, 4, 16);
                sm += __shfl_xor(sm, 8, 16);
                aw[(g * 4 + r) * 20 + li] = f2bf(ev[mc2][r] * __builtin_amdgcn_rcpf(sm));
            }
        }
        // PV: o[i][dh] = sum_j attn[i][j] * v[j][dh], 4 independent MFMAs
        bf16x8 pa0 = (bf16x8)0, pa1 = (bf16x8)0;
        if (g < 2) {
            const unsigned short* ap0 = attw0 + li * 20 + g * 8;
            const unsigned short* ap1 = attw1 + li * 20 + g * 8;
            u16x4 a0lo = *(const u16x4*)ap0, a0hi = *(const u16x4*)(ap0 + 4);
            u16x4 a1lo = *(const u16x4*)ap1, a1hi = *(const u16x4*)(ap1 + 4);
            #pragma unroll
            for (int j = 0; j < 4; ++j) {
                pa0[j] = (short)a0lo[j]; pa0[4 + j] = (short)a0hi[j];
                pa1[j] = (short)a1lo[j]; pa1[4 + j] = (short)a1hi[j];
            }
        }
        f32x4 z00 = {0.f,0.f,0.f,0.f}, z01 = {0.f,0.f,0.f,0.f};
        f32x4 z10 = {0.f,0.f,0.f,0.f}, z11 = {0.f,0.f,0.f,0.f};
        f32x4 po00 = __builtin_amdgcn_mfma_f32_16x16x32_bf16(pa0, bv00, z00, 0, 0, 0);
        f32x4 po10 = __builtin_amdgcn_mfma_f32_16x16x32_bf16(pa1, bv10, z10, 0, 0, 0);
        f32x4 po01 = __builtin_amdgcn_mfma_f32_16x16x32_bf16(pa0, bv01, z01, 0, 0, 0);
        f32x4 po11 = __builtin_amdgcn_mfma_f32_16x16x32_bf16(pa1, bv11, z11, 0, 0, 0);
        int dh0 = li;            // dt = 0 -> always < 28
        int dh1 = 16 + li;       // dt = 1 -> valid if < 28
        #pragma unroll
        for (int r = 0; r < 4; ++r) {
            int i = g * 4 + r;
            ob[i * 232 + cb + dh0]        = f2bf(po00[r]);
            ob[(i + 16) * 232 + cb + dh0] = f2bf(po10[r]);
        }
        if (dh1 < DH) {
            #pragma unroll
            for (int r = 0; r < 4; ++r) {
                int i = g * 4 + r;
                ob[i * 232 + cb + dh1]        = f2bf(po01[r]);
                ob[(i + 16) * 232 + cb + dh1] = f2bf(po11[r]);
            }
        }
    }
    __syncthreads();                                  // B5

    // ---- phase 3: A-hoist from ob, then N-loop directly (no barrier: a3f
    // reads the qs region; oout writes hit xs/ks regions whose last readers
    // finished before B5 -- disjoint). Same B0-pin pipeline as phase 1. ----
    bf16x8 a3f[7];
    #pragma unroll
    for (int kk = 0; kk < 7; ++kk)
        a3f[kk] = *(const bf16x8*)(ob + arow * 232 + kk * 32 + g * 8);

    for (int d = wv >> 1; d < 7; d += 4) {
        int t0 = 2 * d;
        const unsigned short* w0 = wt + (size_t)(42 + t0) * 3584 + l * 8;
        bf16x8 B0[7], B1[7];
        #pragma unroll
        for (int kk = 0; kk < 7; ++kk)
            B0[kk] = *(const bf16x8*)(w0 + kk * 512);
        #pragma unroll
        for (int kk = 0; kk < 7; ++kk)
            B1[kk] = *(const bf16x8*)(w0 + 3584 + kk * 512);
        #pragma unroll
        for (int kk = 0; kk < 7; ++kk)
            asm volatile("" : "+v"(B0[kk]));
        f32x4 acc0 = {0.f, 0.f, 0.f, 0.f}, acc1 = {0.f, 0.f, 0.f, 0.f};
        #pragma unroll
        for (int kk = 0; kk < 7; ++kk)
            acc0 = __builtin_amdgcn_mfma_f32_16x16x32_bf16(a3f[kk], B0[kk], acc0, 0, 0, 0);
        #pragma unroll
        for (int kk = 0; kk < 7; ++kk)
            acc1 = __builtin_amdgcn_mfma_f32_16x16x32_bf16(a3f[kk], B1[kk], acc1, 0, 0, 0);
        int colb = t0 * 16 + li;
        #pragma unroll
        for (int r = 0; r < 4; ++r) {
            int row = mt * 16 + g * 4 + r;
            oout[row * 225 + colb]      = acc0[r];
            oout[row * 225 + colb + 16] = acc1[r];
        }
    }
    __syncthreads();                                  // B6

    // ---- final: out[b][ch][h][w] = oout[row][ch] + bo[ch], float2 stores ----
    {
        float* outb = out + ((size_t)bi * CC << 10);
        for (int q = tid; q < CC * NWIN; q += 512) {
            int ch = q >> 4, wx = q & 15;
            int wi = wx >> 2, wj = wx & 3;
            int h = wi * 8 + mr, w0 = wj * 8 + hq * 2;
            float b = bo[ch];
            float2 v2;
            v2.x = oout[wx * 225 + ch] + b;          // mc2 = 0
            v2.y = oout[(wx + 16) * 225 + ch] + b;   // mc2 = 1
            *(float2*)(outb + (ch << 10) + (h << 5) + w0) = v2;
        }
    }
}

extern "C" void kernel_launch(void* const* d_in, const int* in_sizes, int n_in,
                              void* d_out, int out_size, void* d_ws, size_t ws_size,
                              hipStream_t stream) {
    const float* x   = (const float*)d_in[0];
    const float* Wq  = (const float*)d_in[1];
    const float* Wk  = (const float*)d_in[2];
    const float* Wv  = (const float*)d_in[3];
    const float* Wo  = (const float*)d_in[4];
    const float* bo  = (const float*)d_in[5];
    const float* pos = (const float*)d_in[6];
    const float* scl = (const float*)d_in[7];
    float* out = (float*)d_out;
    unsigned short* wt = (unsigned short*)d_ws;   // 4*224*224*2 = 401408 B

    prep_weights<<<dim3((4 * CC * CC + 255) / 256), dim3(256), 0, stream>>>(Wq, Wk, Wv, Wo, wt);

    (void)hipFuncSetAttribute((const void*)attn_fused,
                              hipFuncAttributeMaxDynamicSharedMemorySize, SMEM_BYTES);
    attn_fused<<<dim3(NB * 8 * 4), dim3(512), SMEM_BYTES, stream>>>(x, wt, bo, pos, scl, out);
}

// Round 17
// 145.760 us; speedup vs baseline: 2.4913x; 2.4913x over previous
//
#include <hip/hip_runtime.h>
#include <stdint.h>

#define NB   128    // batch
#define CC   224    // channels
#define NWIN 16     // windows
#define DH   28     // head dim
#define NHEADS 8

using bf16x8 = __attribute__((ext_vector_type(8))) short;
using u16x4  = __attribute__((ext_vector_type(4))) unsigned short;
using f32x4  = __attribute__((ext_vector_type(4))) float;

__device__ inline unsigned short f2bf(float f) {
    union { float f; unsigned u; } v; v.f = f;
    unsigned u = v.u;
    u += 0x7fffu + ((u >> 16) & 1u);
    return (unsigned short)(u >> 16);
}

// ---- prep: weights -> bf16 in MFMA-native chunk layout ----
// chunk c = (sel*14 + ntl)*7 + kk  (sel 0..3 = Q,K,V,O; ntl 0..13; kk 0..6)
// within chunk: element (lane l, j) = W[k][n],  n = ntl*16 + (l&15),
//               k = kk*32 + (l>>4)*8 + j.
// A wave's B-fragment load for (ntl,kk) is ONE contiguous 1KB read at
// wt + c*512 + l*8.
__global__ void prep_weights(const float* __restrict__ Wq, const float* __restrict__ Wk,
                             const float* __restrict__ Wv, const float* __restrict__ Wo,
                             unsigned short* __restrict__ wt) {
    int e = blockIdx.x * blockDim.x + threadIdx.x;
    if (e >= 4 * CC * CC) return;
    int c   = e >> 9;          // chunk 0..391
    int r   = e & 511;
    int l   = r >> 3, j = r & 7;
    int kk  = c % 7;
    int t   = c / 7;           // sel*14 + ntl
    int sel = t / 14, ntl = t % 14;
    int n = ntl * 16 + (l & 15);
    int k = kk * 32 + (l >> 4) * 8 + j;
    const float* W = (sel == 0) ? Wq : (sel == 1) ? Wk : (sel == 2) ? Wv : Wo;
    wt[e] = f2bf(W[k * CC + n]);
}

// ---- shared memory layout (bytes), 32-position block ----
// Rows: row = widx + 16*mc2  (widx = window 0..15, mc2 = local col 0..1)
// Overlays (barrier-separated):
//   qs region:  qs (phase1 Q out)  -> ob (phase2 out / phase3 A in)
//   xs region:  xs (x staging)     -> vt (phase1 V out, [ch][row] w=40) -> oout (w/ ks)
//   ks region:  ks (phase1 K out)  -> attw1 (phase2b, ks dead after B4) -> oout tail
#define QS_OFF   0        // ushort [32][232] = 14848 B
#define XS_OFF   14848    // max(xs [32][232]=14848, vt [224][40]=17920) = 17920 B
#define KS_OFF   32768    // ushort [32][232] = 14848 B
#define ATT_OFF  47616    // ushort [8 waves][16][20] = 5120 B
#define SMEM_BYTES 52736
// oout: float [32][225] = 28800 B at XS_OFF (14848..43647 < 47616)
// 3 blocks/CU: 3 x 52736 = 158208 <= 163840

__global__ void __launch_bounds__(512, 6) attn_fused(
    const float* __restrict__ x, const unsigned short* __restrict__ wt,
    const float* __restrict__ bo, const float* __restrict__ pos,
    const float* __restrict__ scale, float* __restrict__ out)
{
    extern __shared__ char smem[];
    unsigned short* qs   = (unsigned short*)(smem + QS_OFF);
    unsigned short* xs   = (unsigned short*)(smem + XS_OFF);
    unsigned short* ks   = (unsigned short*)(smem + KS_OFF);
    unsigned short* att  = (unsigned short*)(smem + ATT_OFF);
    unsigned short* vt   = xs;                       // after B2
    unsigned short* ob   = qs;                       // after B4
    float*          oout = (float*)(smem + XS_OFF);  // after B5 + a3f hoist

    const int tid = threadIdx.x;
    const int wv  = tid >> 6;        // wave 0..7
    const int l   = tid & 63;
    const int g   = l >> 4;          // 0..3
    const int li  = l & 15;

    // XCD-aware decode: the 4 hq-siblings of each (bi,mr) sit adjacently on
    // one XCD (bid%8 = XCD round-robin) so partial-line writes merge in L2.
    const int bid = blockIdx.x;
    const int xcd = bid & 7;
    const int idx = bid >> 3;        // 0..511 within XCD
    const int hq  = idx & 3;         // column pair {hq*2, hq*2+1}
    const int wg  = (xcd << 7) + (idx >> 2);   // 0..1023
    const int bi  = wg >> 3;
    const int mr  = wg & 7;

    // ---- prologue: stage x -> LDS bf16, rows widx + 16*mc2 ----
    {
        const float* xb = x + ((size_t)bi * CC << 10);
        for (int q = tid; q < CC * NWIN; q += 512) {
            int ch = q >> 4, wx = q & 15;
            int wi = wx >> 2, wj = wx & 3;
            int h = wi * 8 + mr, w0 = wj * 8 + hq * 2;
            float2 v2 = *(const float2*)(xb + (ch << 10) + (h << 5) + w0);
            xs[wx * 232 + ch]        = f2bf(v2.x);   // mc2 = 0
            xs[(wx + 16) * 232 + ch] = f2bf(v2.y);   // mc2 = 1
        }
    }
    const float scl = scale[0];
    __syncthreads();                                  // B1

    // ---- phase 1 A-hoist (xs dead after this) ----
    const int mt = wv & 1;
    const int arow = mt * 16 + li;
    bf16x8 a1f[7];
    #pragma unroll
    for (int kk = 0; kk < 7; ++kk)
        a1f[kk] = *(const bf16x8*)(xs + arow * 232 + kk * 32 + g * 8);
    __syncthreads();                                  // B2 (xs -> vt)

    // ---- phase 1 N-loop: Q,K,V = x @ Wt.  Dual-N (coalesced chunk loads):
    // pair (t0, t0+1) shares sel (boundaries 14, 28 even); 2 independent
    // MFMA chains; twin waves (2k,2k+1) share chunk streams (L1-friendly).
    for (int d = wv >> 1; d < 21; d += 4) {
        int t0 = 2 * d;
        int sel = t0 / 14, ntl0 = t0 % 14;
        const unsigned short* w0 = wt + (size_t)t0 * 3584 + l * 8;  // t0*7*512
        f32x4 acc0 = {0.f, 0.f, 0.f, 0.f}, acc1 = {0.f, 0.f, 0.f, 0.f};
        #pragma unroll
        for (int kk = 0; kk < 7; ++kk) {
            bf16x8 bf0 = *(const bf16x8*)(w0 + kk * 512);
            bf16x8 bf1 = *(const bf16x8*)(w0 + 3584 + kk * 512);
            acc0 = __builtin_amdgcn_mfma_f32_16x16x32_bf16(a1f[kk], bf0, acc0, 0, 0, 0);
            acc1 = __builtin_amdgcn_mfma_f32_16x16x32_bf16(a1f[kk], bf1, acc1, 0, 0, 0);
        }
        int colb = ntl0 * 16 + li;
        #pragma unroll
        for (int r = 0; r < 4; ++r) {
            int row = mt * 16 + g * 4 + r;
            float v0 = acc0[r], v1 = acc1[r];
            if (sel == 0) {
                qs[row * 232 + colb]      = f2bf(v0 * scl);
                qs[row * 232 + colb + 16] = f2bf(v1 * scl);
            } else if (sel == 1) {
                ks[row * 232 + colb]      = f2bf(v0);
                ks[row * 232 + colb + 16] = f2bf(v1);
            } else {
                vt[colb * 40 + row]        = f2bf(v0);   // [ch][row]
                vt[(colb + 16) * 40 + row] = f2bf(v1);
            }
        }
    }
    __syncthreads();                                  // B3

    // ---- phase 2a: QK^T for both mc2 (reads qs/ks), pos prefetch ----
    const int hd = wv;
    const int cb = hd * DH;
    float pv4[4];
    #pragma unroll
    for (int r = 0; r < 4; ++r)
        pv4[r] = pos[(hd * 16 + g * 4 + r) * 16 + li];
    f32x4 sim[2];
    #pragma unroll
    for (int mc2 = 0; mc2 < 2; ++mc2) {
        int rowq = li + mc2 * 16;
        bf16x8 aq, bk;
        const unsigned short* qp = qs + rowq * 232 + cb + g * 8;
        const unsigned short* kp = ks + rowq * 232 + cb + g * 8;
        u16x4 qlo = *(const u16x4*)qp, qhi = *(const u16x4*)(qp + 4);
        u16x4 klo = *(const u16x4*)kp, khi = *(const u16x4*)(kp + 4);
        if (g == 3) { qhi = (u16x4)0; khi = (u16x4)0; }  // k >= 28 invalid
        #pragma unroll
        for (int j = 0; j < 4; ++j) {
            aq[j] = (short)qlo[j]; aq[4 + j] = (short)qhi[j];
            bk[j] = (short)klo[j]; bk[4 + j] = (short)khi[j];
        }
        f32x4 z = {0.f, 0.f, 0.f, 0.f};
        sim[mc2] = __builtin_amdgcn_mfma_f32_16x16x32_bf16(aq, bk, z, 0, 0, 0);
    }
    __syncthreads();                                  // B4 (qs -> ob; ks dead)

    // ---- phase 2b: softmax (both mc2 interleaved) + PV (4 indep MFMAs) ----
    // No max-subtraction: s = q.k + pos is bounded (|s| ~< 6 by construction)
    // so exp(s) is safe in f32 and softmax is algebraically identical.
    // attw1 lives in the dead ks region (oout only overlays it after B5).
    {
        unsigned short* attw0 = att + wv * 320;
        unsigned short* attw1 = ks  + wv * 320;
        // hoist V-fragment loads (independent of softmax)
        bf16x8 bv00, bv01, bv10, bv11;
        if (g < 2) {
            bv00 = *(const bf16x8*)(vt + (cb + li) * 40      + g * 8);
            bv01 = *(const bf16x8*)(vt + (cb + 16 + li) * 40 + g * 8);
            bv10 = *(const bf16x8*)(vt + (cb + li) * 40      + 16 + g * 8);
            bv11 = *(const bf16x8*)(vt + (cb + 16 + li) * 40 + 16 + g * 8);
        } else {
            bv00 = (bf16x8)0; bv01 = (bf16x8)0; bv10 = (bf16x8)0; bv11 = (bf16x8)0;
        }
        // softmax: 8 independent rows (2 mc2 x 4 r), chains interleave
        float ev[2][4];
        #pragma unroll
        for (int mc2 = 0; mc2 < 2; ++mc2)
            #pragma unroll
            for (int r = 0; r < 4; ++r)
                ev[mc2][r] = __expf(sim[mc2][r] + pv4[r]);
        #pragma unroll
        for (int mc2 = 0; mc2 < 2; ++mc2) {
            unsigned short* aw = mc2 ? attw1 : attw0;
            #pragma unroll
            for (int r = 0; r < 4; ++r) {
                float sm = ev[mc2][r];
                sm += __shfl_xor(sm, 1, 16);
                sm += __shfl_xor(sm, 2, 16);
                sm += __shfl_xor(sm, 4, 16);
                sm += __shfl_xor(sm, 8, 16);
                aw[(g * 4 + r) * 20 + li] = f2bf(ev[mc2][r] * __builtin_amdgcn_rcpf(sm));
            }
        }
        // PV: o[i][dh] = sum_j attn[i][j] * v[j][dh], 4 independent MFMAs
        bf16x8 pa0 = (bf16x8)0, pa1 = (bf16x8)0;
        if (g < 2) {
            const unsigned short* ap0 = attw0 + li * 20 + g * 8;
            const unsigned short* ap1 = attw1 + li * 20 + g * 8;
            u16x4 a0lo = *(const u16x4*)ap0, a0hi = *(const u16x4*)(ap0 + 4);
            u16x4 a1lo = *(const u16x4*)ap1, a1hi = *(const u16x4*)(ap1 + 4);
            #pragma unroll
            for (int j = 0; j < 4; ++j) {
                pa0[j] = (short)a0lo[j]; pa0[4 + j] = (short)a0hi[j];
                pa1[j] = (short)a1lo[j]; pa1[4 + j] = (short)a1hi[j];
            }
        }
        f32x4 z00 = {0.f,0.f,0.f,0.f}, z01 = {0.f,0.f,0.f,0.f};
        f32x4 z10 = {0.f,0.f,0.f,0.f}, z11 = {0.f,0.f,0.f,0.f};
        f32x4 po00 = __builtin_amdgcn_mfma_f32_16x16x32_bf16(pa0, bv00, z00, 0, 0, 0);
        f32x4 po10 = __builtin_amdgcn_mfma_f32_16x16x32_bf16(pa1, bv10, z10, 0, 0, 0);
        f32x4 po01 = __builtin_amdgcn_mfma_f32_16x16x32_bf16(pa0, bv01, z01, 0, 0, 0);
        f32x4 po11 = __builtin_amdgcn_mfma_f32_16x16x32_bf16(pa1, bv11, z11, 0, 0, 0);
        int dh0 = li;            // dt = 0 -> always < 28
        int dh1 = 16 + li;       // dt = 1 -> valid if < 28
        #pragma unroll
        for (int r = 0; r < 4; ++r) {
            int i = g * 4 + r;
            ob[i * 232 + cb + dh0]        = f2bf(po00[r]);
            ob[(i + 16) * 232 + cb + dh0] = f2bf(po10[r]);
        }
        if (dh1 < DH) {
            #pragma unroll
            for (int r = 0; r < 4; ++r) {
                int i = g * 4 + r;
                ob[i * 232 + cb + dh1]        = f2bf(po01[r]);
                ob[(i + 16) * 232 + cb + dh1] = f2bf(po11[r]);
            }
        }
    }
    __syncthreads();                                  // B5

    // ---- phase 3: A-hoist from ob, then N-loop directly (no barrier: a3f
    // reads the qs region; oout writes hit xs/ks regions whose last readers
    // (vt in 2b, attw1 in 2b) finished before B5 -- disjoint). ----
    bf16x8 a3f[7];
    #pragma unroll
    for (int kk = 0; kk < 7; ++kk)
        a3f[kk] = *(const bf16x8*)(ob + arow * 232 + kk * 32 + g * 8);

    for (int d = wv >> 1; d < 7; d += 4) {
        int t0 = 2 * d;
        const unsigned short* w0 = wt + (size_t)(42 + t0) * 3584 + l * 8;
        f32x4 acc0 = {0.f, 0.f, 0.f, 0.f}, acc1 = {0.f, 0.f, 0.f, 0.f};
        #pragma unroll
        for (int kk = 0; kk < 7; ++kk) {
            bf16x8 bf0 = *(const bf16x8*)(w0 + kk * 512);
            bf16x8 bf1 = *(const bf16x8*)(w0 + 3584 + kk * 512);
            acc0 = __builtin_amdgcn_mfma_f32_16x16x32_bf16(a3f[kk], bf0, acc0, 0, 0, 0);
            acc1 = __builtin_amdgcn_mfma_f32_16x16x32_bf16(a3f[kk], bf1, acc1, 0, 0, 0);
        }
        int colb = t0 * 16 + li;
        #pragma unroll
        for (int r = 0; r < 4; ++r) {
            int row = mt * 16 + g * 4 + r;
            oout[row * 225 + colb]      = acc0[r];
            oout[row * 225 + colb + 16] = acc1[r];
        }
    }
    __syncthreads();                                  // B6

    // ---- final: out[b][ch][h][w] = oout[row][ch] + bo[ch], float2 stores ----
    {
        float* outb = out + ((size_t)bi * CC << 10);
        for (int q = tid; q < CC * NWIN; q += 512) {
            int ch = q >> 4, wx = q & 15;
            int wi = wx >> 2, wj = wx & 3;
            int h = wi * 8 + mr, w0 = wj * 8 + hq * 2;
            float b = bo[ch];
            float2 v2;
            v2.x = oout[wx * 225 + ch] + b;          // mc2 = 0
            v2.y = oout[(wx + 16) * 225 + ch] + b;   // mc2 = 1
            *(float2*)(outb + (ch << 10) + (h << 5) + w0) = v2;
        }
    }
}

extern "C" void kernel_launch(void* const* d_in, const int* in_sizes, int n_in,
                              void* d_out, int out_size, void* d_ws, size_t ws_size,
                              hipStream_t stream) {
    const float* x   = (const float*)d_in[0];
    const float* Wq  = (const float*)d_in[1];
    const float* Wk  = (const float*)d_in[2];
    const float* Wv  = (const float*)d_in[3];
    const float* Wo  = (const float*)d_in[4];
    const float* bo  = (const float*)d_in[5];
    const float* pos = (const float*)d_in[6];
    const float* scl = (const float*)d_in[7];
    float* out = (float*)d_out;
    unsigned short* wt = (unsigned short*)d_ws;   // 4*224*224*2 = 401408 B

    prep_weights<<<dim3((4 * CC * CC + 255) / 256), dim3(256), 0, stream>>>(Wq, Wk, Wv, Wo, wt);

    (void)hipFuncSetAttribute((const void*)attn_fused,
                              hipFuncAttributeMaxDynamicSharedMemorySize, SMEM_BYTES);
    attn_fused<<<dim3(NB * 8 * 4), dim3(512), SMEM_BYTES, stream>>>(x, wt, bo, pos, scl, out);
}